// Round 6
// baseline (1816.707 us; speedup 1.0000x reference)
//
#include <hip/hip_runtime.h>
#include <math.h>

__device__ __forceinline__ float sigf(float x) { return 1.0f / (1.0f + expf(-x)); }
__device__ __forceinline__ float4 f4fma(float s, float4 b, float4 a) {
  return make_float4(fmaf(s, b.x, a.x), fmaf(s, b.y, a.y), fmaf(s, b.z, a.z), fmaf(s, b.w, a.w));
}
__device__ __forceinline__ void wave_red2(float4& v) {
  v.x += __shfl_xor(v.x, 16); v.y += __shfl_xor(v.y, 16);
  v.z += __shfl_xor(v.z, 16); v.w += __shfl_xor(v.w, 16);
  v.x += __shfl_xor(v.x, 32); v.y += __shfl_xor(v.y, 32);
  v.z += __shfl_xor(v.z, 32); v.w += __shfl_xor(v.w, 32);
}

// ---------------- Encoder GEMM1: C = relu(X @ W + b) ----------------
// X:[16384,1024] W:[1024,512]; 64x128 tiles, grid 1024 (4 WG/CU)
__global__ __launch_bounds__(256) void k_gemm1(const float* __restrict__ X,
                                               const float* __restrict__ W,
                                               const float* __restrict__ Bv,
                                               float* __restrict__ C)
{
  const int K = 1024, N = 512;
  __shared__ float As[16][68];
  __shared__ float Bs[16][132];
  const int tid = threadIdx.x;
  const int bm = blockIdx.x >> 2;   // 256 row blocks of 64
  const int bn = blockIdx.x & 3;    // 4 col blocks of 128
  const int ty = tid >> 4, tx = tid & 15;      // micro 4r x (4+4)c
  const int ar = tid & 63, ac4 = (tid >> 6) * 4;
  const int bk = tid >> 4, bc8 = (tid & 15) * 8;
  const float* Xb = X + (size_t)(bm * 64 + ar) * K;
  float acc[4][8];
#pragma unroll
  for (int i = 0; i < 4; i++)
#pragma unroll
    for (int j = 0; j < 8; j++) acc[i][j] = 0.f;

  for (int k0 = 0; k0 < K; k0 += 16) {
    float4 av = *(const float4*)(Xb + k0 + ac4);
    float4 b0 = *(const float4*)(W + (size_t)(k0 + bk) * N + bn * 128 + bc8);
    float4 b1 = *(const float4*)(W + (size_t)(k0 + bk) * N + bn * 128 + bc8 + 4);
    As[ac4 + 0][ar] = av.x; As[ac4 + 1][ar] = av.y;
    As[ac4 + 2][ar] = av.z; As[ac4 + 3][ar] = av.w;
    *(float4*)(&Bs[bk][bc8]) = b0;
    *(float4*)(&Bs[bk][bc8 + 4]) = b1;
    __syncthreads();
#pragma unroll
    for (int kk = 0; kk < 16; kk++) {
      float4 a = *(const float4*)(&As[kk][ty * 4]);
      float4 bA = *(const float4*)(&Bs[kk][tx * 4]);
      float4 bB = *(const float4*)(&Bs[kk][64 + tx * 4]);
      float ar4[4] = {a.x, a.y, a.z, a.w};
#pragma unroll
      for (int i = 0; i < 4; i++) {
        acc[i][0] = fmaf(ar4[i], bA.x, acc[i][0]);
        acc[i][1] = fmaf(ar4[i], bA.y, acc[i][1]);
        acc[i][2] = fmaf(ar4[i], bA.z, acc[i][2]);
        acc[i][3] = fmaf(ar4[i], bA.w, acc[i][3]);
        acc[i][4] = fmaf(ar4[i], bB.x, acc[i][4]);
        acc[i][5] = fmaf(ar4[i], bB.y, acc[i][5]);
        acc[i][6] = fmaf(ar4[i], bB.z, acc[i][6]);
        acc[i][7] = fmaf(ar4[i], bB.w, acc[i][7]);
      }
    }
    __syncthreads();
  }
  const int crow0 = bm * 64 + ty * 4;
  const int ccolA = bn * 128 + tx * 4;
  const int ccolB = ccolA + 64;
  float4 bvA = *(const float4*)(Bv + ccolA);
  float4 bvB = *(const float4*)(Bv + ccolB);
#pragma unroll
  for (int i = 0; i < 4; i++) {
    float4 vA = make_float4(acc[i][0] + bvA.x, acc[i][1] + bvA.y,
                            acc[i][2] + bvA.z, acc[i][3] + bvA.w);
    float4 vB = make_float4(acc[i][4] + bvB.x, acc[i][5] + bvB.y,
                            acc[i][6] + bvB.z, acc[i][7] + bvB.w);
    vA.x = fmaxf(vA.x, 0.f); vA.y = fmaxf(vA.y, 0.f);
    vA.z = fmaxf(vA.z, 0.f); vA.w = fmaxf(vA.w, 0.f);
    vB.x = fmaxf(vB.x, 0.f); vB.y = fmaxf(vB.y, 0.f);
    vB.z = fmaxf(vB.z, 0.f); vB.w = fmaxf(vB.w, 0.f);
    *(float4*)(&C[(size_t)(crow0 + i) * N + ccolA]) = vA;
    *(float4*)(&C[(size_t)(crow0 + i) * N + ccolB]) = vB;
  }
}

// ---------------- Encoder GEMM2: zp = C1 @ W2 + b2 ----------------
// 32x128 tiles, grid 512. zp layout [512][32][128] (stride 4096)
__global__ __launch_bounds__(256) void k_gemm2(const float* __restrict__ A,
                                               const float* __restrict__ W,
                                               const float* __restrict__ Bv,
                                               float* __restrict__ zp)
{
  const int K = 512, N = 128;
  __shared__ float As[16][36];
  __shared__ float Bs[16][132];
  const int tid = threadIdx.x;
  const int bm = blockIdx.x;
  const int ty = tid >> 4, tx = tid & 15;   // micro 2r x (4+4)c
  const int ar = tid & 31, ac4 = ((tid >> 5) & 3) * 4;  // 128 thr stage A
  const int bk = tid >> 4, bc8 = (tid & 15) * 8;
  float acc[2][8];
#pragma unroll
  for (int i = 0; i < 2; i++)
#pragma unroll
    for (int j = 0; j < 8; j++) acc[i][j] = 0.f;

  for (int k0 = 0; k0 < K; k0 += 16) {
    if (tid < 128) {
      float4 av = *(const float4*)(A + (size_t)(bm * 32 + ar) * K + k0 + ac4);
      As[ac4 + 0][ar] = av.x; As[ac4 + 1][ar] = av.y;
      As[ac4 + 2][ar] = av.z; As[ac4 + 3][ar] = av.w;
    }
    *(float4*)(&Bs[bk][bc8]) = *(const float4*)(W + (size_t)(k0 + bk) * N + bc8);
    *(float4*)(&Bs[bk][bc8 + 4]) = *(const float4*)(W + (size_t)(k0 + bk) * N + bc8 + 4);
    __syncthreads();
#pragma unroll
    for (int kk = 0; kk < 16; kk++) {
      float a0 = As[kk][ty * 2], a1 = As[kk][ty * 2 + 1];
      float4 bA = *(const float4*)(&Bs[kk][tx * 4]);
      float4 bB = *(const float4*)(&Bs[kk][64 + tx * 4]);
      acc[0][0] = fmaf(a0, bA.x, acc[0][0]); acc[0][1] = fmaf(a0, bA.y, acc[0][1]);
      acc[0][2] = fmaf(a0, bA.z, acc[0][2]); acc[0][3] = fmaf(a0, bA.w, acc[0][3]);
      acc[0][4] = fmaf(a0, bB.x, acc[0][4]); acc[0][5] = fmaf(a0, bB.y, acc[0][5]);
      acc[0][6] = fmaf(a0, bB.z, acc[0][6]); acc[0][7] = fmaf(a0, bB.w, acc[0][7]);
      acc[1][0] = fmaf(a1, bA.x, acc[1][0]); acc[1][1] = fmaf(a1, bA.y, acc[1][1]);
      acc[1][2] = fmaf(a1, bA.z, acc[1][2]); acc[1][3] = fmaf(a1, bA.w, acc[1][3]);
      acc[1][4] = fmaf(a1, bB.x, acc[1][4]); acc[1][5] = fmaf(a1, bB.y, acc[1][5]);
      acc[1][6] = fmaf(a1, bB.z, acc[1][6]); acc[1][7] = fmaf(a1, bB.w, acc[1][7]);
    }
    __syncthreads();
  }
  const int ccolA = tx * 4, ccolB = ccolA + 64;
  float4 bvA = *(const float4*)(Bv + ccolA);
  float4 bvB = *(const float4*)(Bv + ccolB);
#pragma unroll
  for (int i = 0; i < 2; i++) {
    int r = bm * 32 + ty * 2 + i;
    int b = r >> 5, tt = r & 31;
    float4 vA = make_float4(acc[i][0] + bvA.x, acc[i][1] + bvA.y,
                            acc[i][2] + bvA.z, acc[i][3] + bvA.w);
    float4 vB = make_float4(acc[i][4] + bvB.x, acc[i][5] + bvB.y,
                            acc[i][6] + bvB.z, acc[i][7] + bvB.w);
    *(float4*)(&zp[(size_t)b * 4096 + tt * 128 + ccolA]) = vA;
    *(float4*)(&zp[(size_t)b * 4096 + tt * 128 + ccolB]) = vB;
  }
}

// ---------------- Gram + softmax precompute (+ Mk/gacc slot-0 init) ----------------
__global__ __launch_bounds__(256) void k_gram(const float* __restrict__ zp,
                                              float* __restrict__ warr,
                                              float* __restrict__ wc,
                                              const float* __restrict__ cgp,
                                              const float* __restrict__ cbp,
                                              const float* __restrict__ kb,
                                              float* __restrict__ Mk,
                                              float* __restrict__ gacc)
{
  __shared__ float zl[32][128];
  __shared__ float sg[32][32];
  int b = blockIdx.x, tid = threadIdx.x;
  const float* zb = zp + (size_t)b * 4096;
  for (int i = tid; i < 32 * 128; i += 256) (&zl[0][0])[i] = zb[i];
  // init Mk slot 0 = kb, gacc slot 0 = 0
  Mk[(size_t)b * 8192 + tid] = kb[tid];
  if (tid == 0) gacc[b * 32] = 0.f;
  __syncthreads();
  for (int p = tid; p < 496; p += 256) {
    int t = 1;
    while (p >= t * (t + 1) / 2) t++;
    int tp = p - t * (t - 1) / 2;
    const float* za = &zl[t][0];
    const float* zc = &zl[tp][0];
    float s = 0.f;
#pragma unroll 4
    for (int c = 0; c < 128; c += 4) {
      s += za[c] * zc[c] + za[c + 1] * zc[c + 1] + za[c + 2] * zc[c + 2] + za[c + 3] * zc[c + 3];
    }
    sg[t][tp] = s;
  }
  __syncthreads();
  if (tid >= 1 && tid < 32) {
    int t = tid;
    float cg = cgp[0], cb = cbp[0];
    float m = -3.0e38f;
    for (int tp = 0; tp < t; tp++) m = fmaxf(m, sg[t][tp]);
    float se = 0.f;
    for (int tp = 0; tp < t; tp++) se += expf(sg[t][tp] - m);
    float inv = 1.0f / se;
    float wcs = 0.f;
    for (int tp = 0; tp < t; tp++) {
      float s = sg[t][tp];
      float w = expf(s - m) * inv;
      warr[(size_t)b * 1024 + t * 32 + tp] = w;
      wcs = fmaf(w, sigf(fmaf(s, cg, cb)), wcs);
    }
    wc[b * 32 + t] = wcs;
  }
}

// ---------------- fused per-step kernel ----------------
// grid 512 (rt = blk>>4 [32 x 16 rows], ct = blk&15 [16 x 32 hc]), 256 thr.
// A: keyr = g*P -> LDS As.  B: gates GEMM -> h tile (LDS hs).
// C: keyw partial atomicAdd -> Mk[:,t,:], gate partial atomicAdd -> gacc[:,t].
// D: init Mk[:,t+1,:]=kb, gacc[:,t+1]=0; P_next = sum_tp w[t,tp]*Mk[tp] -> Pw.
__global__ __launch_bounds__(256) void k_step(
    const float* __restrict__ Wx, const float* __restrict__ lb,
    const float* __restrict__ kW, const float* __restrict__ kb,
    const float* __restrict__ gW, const float* __restrict__ gb,
    const float* __restrict__ warr, const float* __restrict__ wc,
    float* __restrict__ Mk, float* __restrict__ gacc,
    const float* __restrict__ Pr, float* __restrict__ Pw,
    float* __restrict__ h, int t)
{
  __shared__ float smem[9984];
  float* As   = smem;          // [257][20] keyr (k-major, 16 rows)
  float* Bs   = smem + 5140;   // [32][100] Wx chunk {i,c,o}
  float* Rb   = smem;          // [4][16][100] reduction (As+Bs dead)
  float* kWs  = smem;          // [16][260] phase C (union)
  float* hs   = smem + 8340;   // [16][36]
  float* wws  = smem + 8916;   // [16][32]
  float* gt16 = smem + 9428;   // [16][16]
  float* gsh  = smem + 9684;   // [16]
  float* Ptmp = smem + 9700;   // [16][17]
  const int tid = threadIdx.x;
  const int rt = blockIdx.x >> 4;
  const int ct = blockIdx.x & 15;
  const int row0 = rt * 16;
  const int hc0 = ct * 32;
  const int c0 = ct * 16;

  // ================ Phase A: keyr -> As ================
  if (t >= 2) {
    if (tid < 16) gsh[tid] = sigf(gacc[(row0 + tid) * 32 + (t - 1)] + gb[0]);
    __syncthreads();
    const int p16 = tid >> 4, r16 = tid & 15;
    const float g = gsh[r16];
#pragma unroll 4
    for (int kg = 0; kg < 16; ++kg) {
      const int k = kg * 16 + p16;
      As[k * 20 + r16] = g * Pr[(size_t)k * 512 + row0 + r16];
    }
    if (p16 == 0) As[256 * 20 + r16] = g * wc[(row0 + r16) * 32 + (t - 1)];
    __syncthreads();
  }

  // ================ Phase B: gates GEMM -> hs ================
  if (t >= 2) {
    const int ksub = tid >> 4;
    const int pos = tid & 15;
    const int rg = pos >> 3;
    const int cg = pos & 7;
    float4 aI[8], aC[8], aO[8];
#pragma unroll
    for (int r = 0; r < 8; r++) {
      aI[r] = make_float4(0.f, 0.f, 0.f, 0.f);
      aC[r] = make_float4(0.f, 0.f, 0.f, 0.f);
      aO[r] = make_float4(0.f, 0.f, 0.f, 0.f);
    }
    for (int c = 0; c < 8; ++c) {
      if (c) __syncthreads();
      {
        const int kkB = tid >> 3, lB = (tid & 7) * 4;
        const float* wrow = Wx + (size_t)(c * 32 + kkB) * 2048;
        *(float4*)&Bs[kkB * 100 + lB]      = *(const float4*)(wrow + hc0 + lB);
        *(float4*)&Bs[kkB * 100 + 32 + lB] = *(const float4*)(wrow + 1024 + hc0 + lB);
        *(float4*)&Bs[kkB * 100 + 64 + lB] = *(const float4*)(wrow + 1536 + hc0 + lB);
      }
      __syncthreads();
#pragma unroll
      for (int i = 0; i < 2; ++i) {
        const int kk = ksub * 2 + i;
        const int kabs = c * 32 + kk;
        float a8[8];
        *(float4*)&a8[0] = *(const float4*)&As[kabs * 20 + rg * 8];
        *(float4*)&a8[4] = *(const float4*)&As[kabs * 20 + rg * 8 + 4];
        float4 bI = *(const float4*)&Bs[kk * 100 + cg * 4];
        float4 bC = *(const float4*)&Bs[kk * 100 + 32 + cg * 4];
        float4 bO = *(const float4*)&Bs[kk * 100 + 64 + cg * 4];
#pragma unroll
        for (int r = 0; r < 8; r++) {
          float a = a8[r];
          aI[r] = f4fma(a, bI, aI[r]);
          aC[r] = f4fma(a, bC, aC[r]);
          aO[r] = f4fma(a, bO, aO[r]);
        }
      }
    }
    if (ksub == 0) {  // tail k=256 from LDS
      float a8[8];
      *(float4*)&a8[0] = *(const float4*)&As[256 * 20 + rg * 8];
      *(float4*)&a8[4] = *(const float4*)&As[256 * 20 + rg * 8 + 4];
      const float* wrow = Wx + (size_t)256 * 2048;
      float4 bI = *(const float4*)(wrow + hc0 + cg * 4);
      float4 bC = *(const float4*)(wrow + 1024 + hc0 + cg * 4);
      float4 bO = *(const float4*)(wrow + 1536 + hc0 + cg * 4);
#pragma unroll
      for (int r = 0; r < 8; r++) {
        float a = a8[r];
        aI[r] = f4fma(a, bI, aI[r]);
        aC[r] = f4fma(a, bC, aC[r]);
        aO[r] = f4fma(a, bO, aO[r]);
      }
    }
#pragma unroll
    for (int r = 0; r < 8; r++) { wave_red2(aI[r]); wave_red2(aC[r]); wave_red2(aO[r]); }
    __syncthreads();  // As/Bs dead -> Rb
    {
      const int wave = tid >> 6, lane = tid & 63;
      if (lane < 16) {
        float* w = &Rb[wave * 1600 + lane * 100];
#pragma unroll
        for (int r = 0; r < 8; r++) {
          *(float4*)&w[r * 12 + 0] = aI[r];
          *(float4*)&w[r * 12 + 4] = aC[r];
          *(float4*)&w[r * 12 + 8] = aO[r];
        }
      }
    }
    __syncthreads();
    {
      const int r = tid >> 4;
      const int hc2 = (tid & 15) * 2;
      const int p = (r >> 3) * 8 + (hc2 >> 2);
      const int base = p * 100 + (r & 7) * 12;
      const int off = hc2 & 3;
      float sI0 = Rb[base + off]     + Rb[1600 + base + off]     + Rb[3200 + base + off]     + Rb[4800 + base + off];
      float sI1 = Rb[base + off + 1] + Rb[1600 + base + off + 1] + Rb[3200 + base + off + 1] + Rb[4800 + base + off + 1];
      float sC0 = Rb[base + 4 + off]     + Rb[1600 + base + 4 + off]     + Rb[3200 + base + 4 + off]     + Rb[4800 + base + 4 + off];
      float sC1 = Rb[base + 4 + off + 1] + Rb[1600 + base + 4 + off + 1] + Rb[3200 + base + 4 + off + 1] + Rb[4800 + base + 4 + off + 1];
      float sO0 = Rb[base + 8 + off]     + Rb[1600 + base + 8 + off]     + Rb[3200 + base + 8 + off]     + Rb[4800 + base + 8 + off];
      float sO1 = Rb[base + 8 + off + 1] + Rb[1600 + base + 8 + off + 1] + Rb[3200 + base + 8 + off + 1] + Rb[4800 + base + 8 + off + 1];
      float iv0 = sI0 + lb[hc0 + hc2],        iv1 = sI1 + lb[hc0 + hc2 + 1];
      float cv0 = sC0 + lb[1024 + hc0 + hc2], cv1 = sC1 + lb[1024 + hc0 + hc2 + 1];
      float ov0 = sO0 + lb[1536 + hc0 + hc2], ov1 = sO1 + lb[1536 + hc0 + hc2 + 1];
      float h0 = sigf(ov0) * tanhf(sigf(iv0) * tanhf(cv0));
      float h1 = sigf(ov1) * tanhf(sigf(iv1) * tanhf(cv1));
      hs[r * 36 + hc2] = h0;
      hs[r * 36 + hc2 + 1] = h1;
      if (t == 32) *(float2*)&h[(size_t)(row0 + r) * 512 + hc0 + hc2] = make_float2(h0, h1);
    }
  } else {  // t < 2: h = act(bias)
    const int r = tid >> 4;
    const int hc2 = (tid & 15) * 2;
    float h0 = sigf(lb[1536 + hc0 + hc2])     * tanhf(sigf(lb[hc0 + hc2])     * tanhf(lb[1024 + hc0 + hc2]));
    float h1 = sigf(lb[1536 + hc0 + hc2 + 1]) * tanhf(sigf(lb[hc0 + hc2 + 1]) * tanhf(lb[1024 + hc0 + hc2 + 1]));
    hs[r * 36 + hc2] = h0;
    hs[r * 36 + hc2 + 1] = h1;
  }
  __syncthreads();  // hs ready

  // ================ Phase C: keyw + gate partials ================
  if (t < 32) {
    const int rC = tid >> 4, cb = tid & 15;
    float4 a16[4];
#pragma unroll
    for (int j = 0; j < 4; j++) a16[j] = make_float4(0.f, 0.f, 0.f, 0.f);
#pragma unroll
    for (int half = 0; half < 2; ++half) {
      __syncthreads();  // kWs region (union with As/Rb) free
      {
        const int rowW = tid >> 4;
        const int cc4 = (tid & 15) * 4;
#pragma unroll
        for (int q = 0; q < 4; ++q) {
          *(float4*)&kWs[rowW * 260 + cc4 + q * 64] =
              *(const float4*)&kW[(size_t)(hc0 + half * 16 + rowW) * 256 + cc4 + q * 64];
        }
      }
      __syncthreads();
#pragma unroll
      for (int kk = 0; kk < 16; ++kk) {
        float a = hs[rC * 36 + half * 16 + kk];
#pragma unroll
        for (int j = 0; j < 4; ++j) {
          float4 b = *(const float4*)&kWs[kk * 260 + j * 64 + cb * 4];
          a16[j] = f4fma(a, b, a16[j]);
        }
      }
    }
    {
      float* mkt = Mk + (size_t)(row0 + rC) * 8192 + t * 256;
#pragma unroll
      for (int j = 0; j < 4; ++j) {
        atomicAdd(&mkt[j * 64 + cb * 4 + 0], a16[j].x);
        atomicAdd(&mkt[j * 64 + cb * 4 + 1], a16[j].y);
        atomicAdd(&mkt[j * 64 + cb * 4 + 2], a16[j].z);
        atomicAdd(&mkt[j * 64 + cb * 4 + 3], a16[j].w);
      }
    }
    {
      float gs = hs[rC * 36 + cb * 2] * gW[hc0 + cb * 2] +
                 hs[rC * 36 + cb * 2 + 1] * gW[hc0 + cb * 2 + 1];
      gt16[rC * 16 + cb] = gs;
    }
    __syncthreads();
    if (tid < 16) {
      float s = 0.f;
#pragma unroll
      for (int p = 0; p < 16; ++p) s += gt16[tid * 16 + p];
      atomicAdd(&gacc[(row0 + tid) * 32 + t], s);
    }

    // ================ Phase D: next-slot init + P ================
    if (t < 31) {
      const int rD = tid >> 4, cD = tid & 15;
      Mk[(size_t)(row0 + rD) * 8192 + (t + 1) * 256 + c0 + cD] = kb[c0 + cD];
      if (ct == 0 && tid < 16) gacc[(row0 + tid) * 32 + (t + 1)] = 0.f;
    }
    if (t >= 1) {
      {
        const int r = tid >> 4, s = tid & 15;
        wws[r * 32 + s]      = (s < t)      ? warr[(size_t)(row0 + r) * 1024 + t * 32 + s] : 0.f;
        wws[r * 32 + 16 + s] = (16 + s < t) ? warr[(size_t)(row0 + r) * 1024 + t * 32 + 16 + s] : 0.f;
      }
      __syncthreads();
      {
        const int rD = tid >> 4, cD = tid & 15;
        const float* mkb = Mk + (size_t)(row0 + rD) * 8192 + c0 + cD;
        const float* wp = &wws[rD * 32];
        float acc = 0.f;
        for (int tp = 0; tp < t; ++tp) acc = fmaf(wp[tp], mkb[tp * 256], acc);
        Ptmp[cD * 17 + rD] = acc;
      }
      __syncthreads();
      {
        const int cW = tid >> 4, rW = tid & 15;
        Pw[(size_t)(c0 + cW) * 512 + row0 + rW] = Ptmp[cW * 17 + rW];
      }
    }
  }
}

// ---------------- final: y = h @ yW + yb, argmax ----------------
__global__ __launch_bounds__(256) void k_y(const float* __restrict__ h,
                                           const float* __restrict__ yW,
                                           const float* __restrict__ yb,
                                           float* __restrict__ out)
{
  int tid = threadIdx.x;
  int wave = tid >> 6, lane = tid & 63;
  int row = blockIdx.x * 4 + wave;
  float a0 = 0.f, a1 = 0.f, a2 = 0.f, a3 = 0.f;
  for (int k = lane; k < 512; k += 64) {
    float hv = h[(size_t)row * 512 + k];
    float4 w4 = *(const float4*)(yW + k * 4);
    a0 = fmaf(hv, w4.x, a0);
    a1 = fmaf(hv, w4.y, a1);
    a2 = fmaf(hv, w4.z, a2);
    a3 = fmaf(hv, w4.w, a3);
  }
#pragma unroll
  for (int off = 32; off > 0; off >>= 1) {
    a0 += __shfl_xor(a0, off);
    a1 += __shfl_xor(a1, off);
    a2 += __shfl_xor(a2, off);
    a3 += __shfl_xor(a3, off);
  }
  if (lane == 0) {
    a0 += yb[0]; a1 += yb[1]; a2 += yb[2]; a3 += yb[3];
    out[row * 4 + 0] = a0;
    out[row * 4 + 1] = a1;
    out[row * 4 + 2] = a2;
    out[row * 4 + 3] = a3;
    int bi = 0; float bv = a0;
    if (a1 > bv) { bv = a1; bi = 1; }
    if (a2 > bv) { bv = a2; bi = 2; }
    if (a3 > bv) { bv = a3; bi = 3; }
    out[2048 + row] = (float)bi;
  }
}

extern "C" void kernel_launch(void* const* d_in, const int* in_sizes, int n_in,
                              void* d_out, int out_size, void* d_ws, size_t ws_size,
                              hipStream_t stream)
{
  const float* x  = (const float*)d_in[0];
  const float* w1 = (const float*)d_in[1];
  const float* b1 = (const float*)d_in[2];
  const float* w2 = (const float*)d_in[3];
  const float* b2 = (const float*)d_in[4];
  const float* Wx = (const float*)d_in[5];
  const float* lb = (const float*)d_in[6];
  const float* kW = (const float*)d_in[7];
  const float* kb = (const float*)d_in[8];
  const float* gW = (const float*)d_in[9];
  const float* gb = (const float*)d_in[10];
  const float* yW = (const float*)d_in[11];
  const float* yb = (const float*)d_in[12];
  const float* cg = (const float*)d_in[13];
  const float* cb = (const float*)d_in[14];
  float* out = (float*)d_out;
  char* ws = (char*)d_ws;
  // ws layout (all scan buffers overlap the dead C1 region [0, 33.55MB)):
  //  C1    @ 0          33554432  (encoder hidden, dead after k_gemm2)
  //    Mk   @ 0          16777216  [512][32][256]
  //    warr @ 16777216   2097152   [512][32][32]
  //    wc   @ 18874368   65536     [512][32]
  //    gacc @ 18939904   65536     [512][32]
  //    P0   @ 19005440   524288    [256][512]
  //    P1   @ 19529728   524288
  //    h    @ 20054016   1048576   [512][512]
  //  zp @ 33554432       8388608   [512][32][128]
  float* C1   = (float*)(ws);
  float* Mk   = (float*)(ws);
  float* warr = (float*)(ws + 16777216);
  float* wcb  = (float*)(ws + 18874368);
  float* gacc = (float*)(ws + 18939904);
  float* P0   = (float*)(ws + 19005440);
  float* P1   = (float*)(ws + 19529728);
  float* h    = (float*)(ws + 20054016);
  float* zp   = (float*)(ws + 33554432);

  hipLaunchKernelGGL(k_gemm1, dim3(1024), dim3(256), 0, stream, x, w1, b1, C1);
  hipLaunchKernelGGL(k_gemm2, dim3(512), dim3(256), 0, stream, C1, w2, b2, zp);
  hipLaunchKernelGGL(k_gram, dim3(512), dim3(256), 0, stream, zp, warr, wcb, cg, cb, kb, Mk, gacc);
  for (int t = 0; t <= 32; t++) {
    float* Pr = (t & 1) ? P1 : P0;
    float* Pw = ((t + 1) & 1) ? P1 : P0;
    hipLaunchKernelGGL(k_step, dim3(512), dim3(256), 0, stream,
                       Wx, lb, kW, kb, gW, gb, warr, wcb, Mk, gacc, Pr, Pw, h, t);
  }
  hipLaunchKernelGGL(k_y, dim3(128), dim3(256), 0, stream, h, yW, yb, out);
}

// Round 7
// 1430.926 us; speedup vs baseline: 1.2696x; 1.2696x over previous
//
#include <hip/hip_runtime.h>
#include <math.h>

__device__ __forceinline__ float sigf(float x) { return 1.0f / (1.0f + expf(-x)); }
__device__ __forceinline__ float4 f4fma(float s, float4 b, float4 a) {
  return make_float4(fmaf(s, b.x, a.x), fmaf(s, b.y, a.y), fmaf(s, b.z, a.z), fmaf(s, b.w, a.w));
}
__device__ __forceinline__ void wave_red16_32(float4& v) {
  v.x += __shfl_xor(v.x, 16); v.y += __shfl_xor(v.y, 16);
  v.z += __shfl_xor(v.z, 16); v.w += __shfl_xor(v.w, 16);
  v.x += __shfl_xor(v.x, 32); v.y += __shfl_xor(v.y, 32);
  v.z += __shfl_xor(v.z, 32); v.w += __shfl_xor(v.w, 32);
}
__device__ __forceinline__ void wave_red8_16_32(float4& v) {
  v.x += __shfl_xor(v.x, 8);  v.y += __shfl_xor(v.y, 8);
  v.z += __shfl_xor(v.z, 8);  v.w += __shfl_xor(v.w, 8);
  wave_red16_32(v);
}

// ---------------- Encoder GEMM1: C = relu(X @ W + b) ----------------
// X:[16384,1024] W:[1024,512]; 64x128 tiles, grid 1024, BK=32, reg-prefetch
__global__ __launch_bounds__(256) void k_gemm1(const float* __restrict__ X,
                                               const float* __restrict__ W,
                                               const float* __restrict__ Bv,
                                               float* __restrict__ C)
{
  const int K = 1024, N = 512;
  __shared__ float As[32][68];
  __shared__ float Bs[32][132];
  const int tid = threadIdx.x;
  const int bm = blockIdx.x >> 2;
  const int bn = blockIdx.x & 3;
  const int ty = tid >> 4, tx = tid & 15;
  const int ar = tid & 63, ac4 = (tid >> 6) * 4;       // X: 2 float4 (k ac4, ac4+16)
  const int wk = tid >> 3, wc = (tid & 7) * 16;        // W: 4 float4
  const float* Xb = X + (size_t)(bm * 64 + ar) * K;
  const float* Wb = W + bn * 128 + wc;
  float acc[4][8];
#pragma unroll
  for (int i = 0; i < 4; i++)
#pragma unroll
    for (int j = 0; j < 8; j++) acc[i][j] = 0.f;

  float4 pa0, pa1, pw0, pw1, pw2, pw3;
  {
    pa0 = *(const float4*)(Xb + ac4);
    pa1 = *(const float4*)(Xb + ac4 + 16);
    const float* wr = Wb + (size_t)wk * N;
    pw0 = *(const float4*)(wr);
    pw1 = *(const float4*)(wr + 4);
    pw2 = *(const float4*)(wr + 8);
    pw3 = *(const float4*)(wr + 12);
  }
  for (int k0 = 0; k0 < K; k0 += 32) {
    if (k0) __syncthreads();
    As[ac4 + 0][ar] = pa0.x; As[ac4 + 1][ar] = pa0.y;
    As[ac4 + 2][ar] = pa0.z; As[ac4 + 3][ar] = pa0.w;
    As[ac4 + 16][ar] = pa1.x; As[ac4 + 17][ar] = pa1.y;
    As[ac4 + 18][ar] = pa1.z; As[ac4 + 19][ar] = pa1.w;
    *(float4*)(&Bs[wk][wc])      = pw0;
    *(float4*)(&Bs[wk][wc + 4])  = pw1;
    *(float4*)(&Bs[wk][wc + 8])  = pw2;
    *(float4*)(&Bs[wk][wc + 12]) = pw3;
    __syncthreads();
    if (k0 < K - 32) {
      const int kn = k0 + 32;
      pa0 = *(const float4*)(Xb + kn + ac4);
      pa1 = *(const float4*)(Xb + kn + ac4 + 16);
      const float* wr = Wb + (size_t)(kn + wk) * N;
      pw0 = *(const float4*)(wr);
      pw1 = *(const float4*)(wr + 4);
      pw2 = *(const float4*)(wr + 8);
      pw3 = *(const float4*)(wr + 12);
    }
#pragma unroll
    for (int kk = 0; kk < 32; kk++) {
      float4 a = *(const float4*)(&As[kk][ty * 4]);
      float4 bA = *(const float4*)(&Bs[kk][tx * 4]);
      float4 bB = *(const float4*)(&Bs[kk][64 + tx * 4]);
      float ar4[4] = {a.x, a.y, a.z, a.w};
#pragma unroll
      for (int i = 0; i < 4; i++) {
        acc[i][0] = fmaf(ar4[i], bA.x, acc[i][0]);
        acc[i][1] = fmaf(ar4[i], bA.y, acc[i][1]);
        acc[i][2] = fmaf(ar4[i], bA.z, acc[i][2]);
        acc[i][3] = fmaf(ar4[i], bA.w, acc[i][3]);
        acc[i][4] = fmaf(ar4[i], bB.x, acc[i][4]);
        acc[i][5] = fmaf(ar4[i], bB.y, acc[i][5]);
        acc[i][6] = fmaf(ar4[i], bB.z, acc[i][6]);
        acc[i][7] = fmaf(ar4[i], bB.w, acc[i][7]);
      }
    }
  }
  const int crow0 = bm * 64 + ty * 4;
  const int ccolA = bn * 128 + tx * 4;
  const int ccolB = ccolA + 64;
  float4 bvA = *(const float4*)(Bv + ccolA);
  float4 bvB = *(const float4*)(Bv + ccolB);
#pragma unroll
  for (int i = 0; i < 4; i++) {
    float4 vA = make_float4(acc[i][0] + bvA.x, acc[i][1] + bvA.y,
                            acc[i][2] + bvA.z, acc[i][3] + bvA.w);
    float4 vB = make_float4(acc[i][4] + bvB.x, acc[i][5] + bvB.y,
                            acc[i][6] + bvB.z, acc[i][7] + bvB.w);
    vA.x = fmaxf(vA.x, 0.f); vA.y = fmaxf(vA.y, 0.f);
    vA.z = fmaxf(vA.z, 0.f); vA.w = fmaxf(vA.w, 0.f);
    vB.x = fmaxf(vB.x, 0.f); vB.y = fmaxf(vB.y, 0.f);
    vB.z = fmaxf(vB.z, 0.f); vB.w = fmaxf(vB.w, 0.f);
    *(float4*)(&C[(size_t)(crow0 + i) * N + ccolA]) = vA;
    *(float4*)(&C[(size_t)(crow0 + i) * N + ccolB]) = vB;
  }
}

// ---------------- Encoder GEMM2: zp = C1 @ W2 + b2; zp [512][32][128] ----------------
__global__ __launch_bounds__(256) void k_gemm2(const float* __restrict__ A,
                                               const float* __restrict__ W,
                                               const float* __restrict__ Bv,
                                               float* __restrict__ zp)
{
  const int K = 512, N = 128;
  __shared__ float As[16][36];
  __shared__ float Bs[16][132];
  const int tid = threadIdx.x;
  const int bm = blockIdx.x;
  const int ty = tid >> 4, tx = tid & 15;
  const int ar = tid & 31, ac4 = ((tid >> 5) & 3) * 4;
  const int bk = tid >> 4, bc8 = (tid & 15) * 8;
  float acc[2][8];
#pragma unroll
  for (int i = 0; i < 2; i++)
#pragma unroll
    for (int j = 0; j < 8; j++) acc[i][j] = 0.f;

  for (int k0 = 0; k0 < K; k0 += 16) {
    if (tid < 128) {
      float4 av = *(const float4*)(A + (size_t)(bm * 32 + ar) * K + k0 + ac4);
      As[ac4 + 0][ar] = av.x; As[ac4 + 1][ar] = av.y;
      As[ac4 + 2][ar] = av.z; As[ac4 + 3][ar] = av.w;
    }
    *(float4*)(&Bs[bk][bc8]) = *(const float4*)(W + (size_t)(k0 + bk) * N + bc8);
    *(float4*)(&Bs[bk][bc8 + 4]) = *(const float4*)(W + (size_t)(k0 + bk) * N + bc8 + 4);
    __syncthreads();
#pragma unroll
    for (int kk = 0; kk < 16; kk++) {
      float a0 = As[kk][ty * 2], a1 = As[kk][ty * 2 + 1];
      float4 bA = *(const float4*)(&Bs[kk][tx * 4]);
      float4 bB = *(const float4*)(&Bs[kk][64 + tx * 4]);
      acc[0][0] = fmaf(a0, bA.x, acc[0][0]); acc[0][1] = fmaf(a0, bA.y, acc[0][1]);
      acc[0][2] = fmaf(a0, bA.z, acc[0][2]); acc[0][3] = fmaf(a0, bA.w, acc[0][3]);
      acc[0][4] = fmaf(a0, bB.x, acc[0][4]); acc[0][5] = fmaf(a0, bB.y, acc[0][5]);
      acc[0][6] = fmaf(a0, bB.z, acc[0][6]); acc[0][7] = fmaf(a0, bB.w, acc[0][7]);
      acc[1][0] = fmaf(a1, bA.x, acc[1][0]); acc[1][1] = fmaf(a1, bA.y, acc[1][1]);
      acc[1][2] = fmaf(a1, bA.z, acc[1][2]); acc[1][3] = fmaf(a1, bA.w, acc[1][3]);
      acc[1][4] = fmaf(a1, bB.x, acc[1][4]); acc[1][5] = fmaf(a1, bB.y, acc[1][5]);
      acc[1][6] = fmaf(a1, bB.z, acc[1][6]); acc[1][7] = fmaf(a1, bB.w, acc[1][7]);
    }
    __syncthreads();
  }
  const int ccolA = tx * 4, ccolB = ccolA + 64;
  float4 bvA = *(const float4*)(Bv + ccolA);
  float4 bvB = *(const float4*)(Bv + ccolB);
#pragma unroll
  for (int i = 0; i < 2; i++) {
    int r = bm * 32 + ty * 2 + i;
    int b = r >> 5, tt = r & 31;
    float4 vA = make_float4(acc[i][0] + bvA.x, acc[i][1] + bvA.y,
                            acc[i][2] + bvA.z, acc[i][3] + bvA.w);
    float4 vB = make_float4(acc[i][4] + bvB.x, acc[i][5] + bvB.y,
                            acc[i][6] + bvB.z, acc[i][7] + bvB.w);
    *(float4*)(&zp[(size_t)b * 4096 + tt * 128 + ccolA]) = vA;
    *(float4*)(&zp[(size_t)b * 4096 + tt * 128 + ccolB]) = vB;
  }
}

// ---------------- Gram + softmax precompute ----------------
__global__ __launch_bounds__(256) void k_gram(const float* __restrict__ zp,
                                              float* __restrict__ warr,
                                              float* __restrict__ wc,
                                              const float* __restrict__ cgp,
                                              const float* __restrict__ cbp)
{
  __shared__ float zl[32][128];
  __shared__ float sg[32][32];
  int b = blockIdx.x, tid = threadIdx.x;
  const float* zb = zp + (size_t)b * 4096;
  for (int i = tid; i < 32 * 128; i += 256) (&zl[0][0])[i] = zb[i];
  __syncthreads();
  for (int p = tid; p < 496; p += 256) {
    int t = 1;
    while (p >= t * (t + 1) / 2) t++;
    int tp = p - t * (t - 1) / 2;
    const float* za = &zl[t][0];
    const float* zc = &zl[tp][0];
    float s = 0.f;
#pragma unroll 4
    for (int c = 0; c < 128; c += 4) {
      s += za[c] * zc[c] + za[c + 1] * zc[c + 1] + za[c + 2] * zc[c + 2] + za[c + 3] * zc[c + 3];
    }
    sg[t][tp] = s;
  }
  __syncthreads();
  if (tid >= 1 && tid < 32) {
    int t = tid;
    float cg = cgp[0], cb = cbp[0];
    float m = -3.0e38f;
    for (int tp = 0; tp < t; tp++) m = fmaxf(m, sg[t][tp]);
    float se = 0.f;
    for (int tp = 0; tp < t; tp++) se += expf(sg[t][tp] - m);
    float inv = 1.0f / se;
    float wcs = 0.f;
    for (int tp = 0; tp < t; tp++) {
      float s = sg[t][tp];
      float w = expf(s - m) * inv;
      warr[(size_t)b * 1024 + t * 32 + tp] = w;
      wcs = fmaf(w, sigf(fmaf(s, cg, cb)), wcs);
    }
    wc[b * 32 + t] = wcs;
  }
}

// ---------------- per-step gates: h = act(keyr @ Wx + b) ----------------
// grid 1024 (32 rt x 32 ct), 256 thr. tile 16r x 16hc x 3g; CK=64 (4 chunks),
// 32-way k-split, micro 8r x 4hc x 3g, reg-prefetch, in-wave + LDS reduce.
__global__ __launch_bounds__(256) void k_gates(const float* __restrict__ Wx,
                                               const float* __restrict__ lb,
                                               const float* __restrict__ keyrT,
                                               float* __restrict__ h, int t)
{
  __shared__ float smem[4608];
  float* As = smem;            // [64][20]
  float* Bs = smem + 1280;     // [64][52] {i,c,o}x16
  float* Rb = smem;            // [4][8][100] reduction (union)
  const int tid = threadIdx.x;
  const int rt = blockIdx.x >> 5;
  const int ct = blockIdx.x & 31;
  const int row0 = rt * 16;
  const int hc0 = ct * 16;

  if (t > 0) {
    const int ksub = tid >> 3;       // 0..31
    const int pos = tid & 7;
    const int rg = pos >> 2;         // rows rg*8..+7
    const int cg = pos & 3;          // hc cg*4..+3
    const int kkS = tid >> 2;        // staging row 0..63
    const int lS = (tid & 3) * 4;    // staging float4 lane
    float4 aI[8], aC[8], aO[8];
#pragma unroll
    for (int r = 0; r < 8; r++) {
      aI[r] = make_float4(0.f, 0.f, 0.f, 0.f);
      aC[r] = make_float4(0.f, 0.f, 0.f, 0.f);
      aO[r] = make_float4(0.f, 0.f, 0.f, 0.f);
    }
    float4 pA, pB0, pB1, pB2;
    {
      pA = *(const float4*)&keyrT[(size_t)kkS * 512 + row0 + lS];
      const float* wrow = Wx + (size_t)kkS * 2048 + hc0 + lS;
      pB0 = *(const float4*)(wrow);
      pB1 = *(const float4*)(wrow + 1024);
      pB2 = *(const float4*)(wrow + 1536);
    }
    for (int c = 0; c < 4; ++c) {
      if (c) __syncthreads();
      *(float4*)&As[kkS * 20 + lS] = pA;
      *(float4*)&Bs[kkS * 52 + lS] = pB0;
      *(float4*)&Bs[kkS * 52 + 16 + lS] = pB1;
      *(float4*)&Bs[kkS * 52 + 32 + lS] = pB2;
      __syncthreads();
      if (c < 3) {
        const int kn = (c + 1) * 64 + kkS;
        pA = *(const float4*)&keyrT[(size_t)kn * 512 + row0 + lS];
        const float* wrow = Wx + (size_t)kn * 2048 + hc0 + lS;
        pB0 = *(const float4*)(wrow);
        pB1 = *(const float4*)(wrow + 1024);
        pB2 = *(const float4*)(wrow + 1536);
      }
#pragma unroll
      for (int i = 0; i < 2; ++i) {
        const int kk = ksub * 2 + i;
        float a8[8];
        *(float4*)&a8[0] = *(const float4*)&As[kk * 20 + rg * 8];
        *(float4*)&a8[4] = *(const float4*)&As[kk * 20 + rg * 8 + 4];
        float4 bI = *(const float4*)&Bs[kk * 52 + cg * 4];
        float4 bC = *(const float4*)&Bs[kk * 52 + 16 + cg * 4];
        float4 bO = *(const float4*)&Bs[kk * 52 + 32 + cg * 4];
#pragma unroll
        for (int r = 0; r < 8; r++) {
          float a = a8[r];
          aI[r] = f4fma(a, bI, aI[r]);
          aC[r] = f4fma(a, bC, aC[r]);
          aO[r] = f4fma(a, bO, aO[r]);
        }
      }
    }
    if (tid < 8) {  // tail k = 256
      float a8[8];
      *(float4*)&a8[0] = *(const float4*)&keyrT[(size_t)256 * 512 + row0 + rg * 8];
      *(float4*)&a8[4] = *(const float4*)&keyrT[(size_t)256 * 512 + row0 + rg * 8 + 4];
      const float* wrow = Wx + (size_t)256 * 2048 + hc0 + cg * 4;
      float4 bI = *(const float4*)(wrow);
      float4 bC = *(const float4*)(wrow + 1024);
      float4 bO = *(const float4*)(wrow + 1536);
#pragma unroll
      for (int r = 0; r < 8; r++) {
        float a = a8[r];
        aI[r] = f4fma(a, bI, aI[r]);
        aC[r] = f4fma(a, bC, aC[r]);
        aO[r] = f4fma(a, bO, aO[r]);
      }
    }
    // in-wave reduction over 8 resident ksubs (lane bits 3,4,5)
#pragma unroll
    for (int r = 0; r < 8; r++) { wave_red8_16_32(aI[r]); wave_red8_16_32(aC[r]); wave_red8_16_32(aO[r]); }
    __syncthreads();  // staging dead -> Rb
    {
      const int wave = tid >> 6, lane = tid & 63;
      if (lane < 8) {
        float* w = &Rb[wave * 800 + lane * 100];
#pragma unroll
        for (int r = 0; r < 8; r++) {
          *(float4*)&w[r * 12 + 0] = aI[r];
          *(float4*)&w[r * 12 + 4] = aC[r];
          *(float4*)&w[r * 12 + 8] = aO[r];
        }
      }
    }
    __syncthreads();
    // finalize: 256 threads -> 16r x 16hc outputs
    {
      const int r = tid >> 4;
      const int hc = tid & 15;
      const int p = (r >> 3) * 4 + (hc >> 2);
      const int base = p * 100 + (r & 7) * 12 + (hc & 3);
      float sI = Rb[base]     + Rb[800 + base]     + Rb[1600 + base]     + Rb[2400 + base];
      float sC = Rb[base + 4] + Rb[800 + base + 4] + Rb[1600 + base + 4] + Rb[2400 + base + 4];
      float sO = Rb[base + 8] + Rb[800 + base + 8] + Rb[1600 + base + 8] + Rb[2400 + base + 8];
      float iv = sI + lb[hc0 + hc];
      float cv = sC + lb[1024 + hc0 + hc];
      float ov = sO + lb[1536 + hc0 + hc];
      h[(size_t)(row0 + r) * 512 + hc0 + hc] = sigf(ov) * tanhf(sigf(iv) * tanhf(cv));
    }
  } else {  // t == 0
    const int r = tid >> 4;
    const int hc = tid & 15;
    float hv = sigf(lb[1536 + hc0 + hc]) * tanhf(sigf(lb[hc0 + hc]) * tanhf(lb[1024 + hc0 + hc]));
    h[(size_t)(row0 + r) * 512 + hc0 + hc] = hv;
  }
}

// ---------------- per-step update: keyw->Mk[t], gate, keyrT ----------------
// grid 512 (32 rt x 16 ct), 256 thr. tile 16r x 16c; CK=64 (8 chunks),
// 16-way k-split, micro 4r x 4c, reg-prefetch.
__global__ __launch_bounds__(256) void k_update(const float* __restrict__ h,
                                                const float* __restrict__ kW,
                                                const float* __restrict__ kb,
                                                const float* __restrict__ gW,
                                                const float* __restrict__ gb,
                                                const float* __restrict__ warr,
                                                const float* __restrict__ wc,
                                                float* __restrict__ Mk,
                                                float* __restrict__ keyrT, int t)
{
  __shared__ float smem[10640];
  float* hs  = smem;           // [16][516]
  float* gWs = smem + 8256;    // [512]
  float* wws = smem + 8768;    // [16][36]
  float* gsh = smem + 9344;    // [16]
  float* kWs = smem + 9360;    // [64][20] chunk
  float* Rb  = smem + 9360;    // [4][16][20] partials (union)
  const int tid = threadIdx.x;
  const int rt = blockIdx.x >> 4;
  const int ct = blockIdx.x & 15;
  const int row0 = rt * 16;
  const int c0 = ct * 16;

  // stage hs (seg-rotated), gWs, wws
  {
    const int r = tid >> 4, seg = tid & 15;
    const float* hrow = h + (size_t)(row0 + r) * 512 + seg * 32;
    float* hd = hs + r * 516 + seg * 32;
#pragma unroll
    for (int q = 0; q < 8; ++q) {
      const int qp = ((q + seg) & 7) * 4;
      *(float4*)&hd[qp] = *(const float4*)&hrow[qp];
    }
    if (tid < 128) *(float4*)&gWs[tid * 4] = *(const float4*)&gW[tid * 4];
    wws[r * 36 + seg]      = (seg < t)      ? warr[(size_t)(row0 + r) * 1024 + t * 32 + seg] : 0.f;
    wws[r * 36 + 16 + seg] = (16 + seg < t) ? warr[(size_t)(row0 + r) * 1024 + t * 32 + 16 + seg] : 0.f;
  }
  const int kkW = tid >> 2, lW = (tid & 3) * 4;
  float4 pW = *(const float4*)&kW[(size_t)kkW * 256 + c0 + lW];
  __syncthreads();

  // keyw GEMM: K=512 in 8 chunks of 64
  const int ksub = tid >> 4, pu = tid & 15, rgu = pu >> 2, cgu = pu & 3;
  float4 au[4];
#pragma unroll
  for (int r = 0; r < 4; r++) au[r] = make_float4(0.f, 0.f, 0.f, 0.f);
  for (int c = 0; c < 8; ++c) {
    if (c) __syncthreads();
    *(float4*)&kWs[kkW * 20 + lW] = pW;
    __syncthreads();
    if (c < 7) pW = *(const float4*)&kW[(size_t)((c + 1) * 64 + kkW) * 256 + c0 + lW];
#pragma unroll
    for (int i = 0; i < 4; ++i) {
      const int kk = ksub * 4 + i;
      float4 b4 = *(const float4*)&kWs[kk * 20 + cgu * 4];
      const int kidx = c * 64 + kk;
#pragma unroll
      for (int jj = 0; jj < 4; ++jj) {
        float a = hs[(rgu * 4 + jj) * 516 + kidx];
        au[jj] = f4fma(a, b4, au[jj]);
      }
    }
  }
#pragma unroll
  for (int r = 0; r < 4; r++) wave_red16_32(au[r]);
  __syncthreads();  // kWs dead -> Rb
  {
    const int wave = tid >> 6, lane = tid & 63;
    if (lane < 16) {
      float* w = &Rb[wave * 320 + lane * 20];
#pragma unroll
      for (int r = 0; r < 4; r++) *(float4*)&w[r * 4] = au[r];
    }
  }
  __syncthreads();
  // Mk write (+kb)
  {
    const int r = tid >> 4, cc = tid & 15;
    const int p = (r >> 2) * 4 + (cc >> 2);
    const int e = p * 20 + (r & 3) * 4 + (cc & 3);
    float v = Rb[e] + Rb[320 + e] + Rb[640 + e] + Rb[960 + e];
    Mk[(size_t)(row0 + r) * 8192 + t * 256 + c0 + cc] = v + kb[c0 + cc];
  }
  // gate dot
  {
    const int r = tid >> 4, seg = tid & 15;
    const float* hp = &hs[r * 516 + seg * 32];
    const float* gp = &gWs[seg * 32];
    float s = 0.f;
#pragma unroll 8
    for (int j = 0; j < 32; ++j) s = fmaf(hp[j], gp[j], s);
    s += __shfl_xor(s, 1); s += __shfl_xor(s, 2);
    s += __shfl_xor(s, 4); s += __shfl_xor(s, 8);
    if (seg == 0) gsh[r] = sigf(s + gb[0]);
  }
  __syncthreads();
  // keyr update (transposed store)
  {
    const int r = tid >> 4, cc = tid & 15;
    const int row = row0 + r;
    if (t == 0) {
      keyrT[(size_t)(c0 + cc) * 512 + row] = 0.f;
      if (ct == 0 && cc == 0) keyrT[(size_t)256 * 512 + row] = 0.f;
    } else {
      float a = 0.f;
      const float* mkb = Mk + (size_t)row * 8192 + c0 + cc;
      const float* wp = &wws[r * 36];
      for (int tp = 0; tp < t; ++tp) a = fmaf(wp[tp], mkb[tp * 256], a);
      float g = gsh[r];
      keyrT[(size_t)(c0 + cc) * 512 + row] = g * a;
      if (ct == 0 && cc == 0)
        keyrT[(size_t)256 * 512 + row] = g * wc[row * 32 + t];
    }
  }
}

// ---------------- final: y = h @ yW + yb, argmax ----------------
__global__ __launch_bounds__(256) void k_y(const float* __restrict__ h,
                                           const float* __restrict__ yW,
                                           const float* __restrict__ yb,
                                           float* __restrict__ out)
{
  int tid = threadIdx.x;
  int wave = tid >> 6, lane = tid & 63;
  int row = blockIdx.x * 4 + wave;
  float a0 = 0.f, a1 = 0.f, a2 = 0.f, a3 = 0.f;
  for (int k = lane; k < 512; k += 64) {
    float hv = h[(size_t)row * 512 + k];
    float4 w4 = *(const float4*)(yW + k * 4);
    a0 = fmaf(hv, w4.x, a0);
    a1 = fmaf(hv, w4.y, a1);
    a2 = fmaf(hv, w4.z, a2);
    a3 = fmaf(hv, w4.w, a3);
  }
#pragma unroll
  for (int off = 32; off > 0; off >>= 1) {
    a0 += __shfl_xor(a0, off);
    a1 += __shfl_xor(a1, off);
    a2 += __shfl_xor(a2, off);
    a3 += __shfl_xor(a3, off);
  }
  if (lane == 0) {
    a0 += yb[0]; a1 += yb[1]; a2 += yb[2]; a3 += yb[3];
    out[row * 4 + 0] = a0;
    out[row * 4 + 1] = a1;
    out[row * 4 + 2] = a2;
    out[row * 4 + 3] = a3;
    int bi = 0; float bv = a0;
    if (a1 > bv) { bv = a1; bi = 1; }
    if (a2 > bv) { bv = a2; bi = 2; }
    if (a3 > bv) { bv = a3; bi = 3; }
    out[2048 + row] = (float)bi;
  }
}

extern "C" void kernel_launch(void* const* d_in, const int* in_sizes, int n_in,
                              void* d_out, int out_size, void* d_ws, size_t ws_size,
                              hipStream_t stream)
{
  const float* x  = (const float*)d_in[0];
  const float* w1 = (const float*)d_in[1];
  const float* b1 = (const float*)d_in[2];
  const float* w2 = (const float*)d_in[3];
  const float* b2 = (const float*)d_in[4];
  const float* Wx = (const float*)d_in[5];
  const float* lb = (const float*)d_in[6];
  const float* kW = (const float*)d_in[7];
  const float* kb = (const float*)d_in[8];
  const float* gW = (const float*)d_in[9];
  const float* gb = (const float*)d_in[10];
  const float* yW = (const float*)d_in[11];
  const float* yb = (const float*)d_in[12];
  const float* cg = (const float*)d_in[13];
  const float* cb = (const float*)d_in[14];
  float* out = (float*)d_out;
  char* ws = (char*)d_ws;
  // ws layout:
  //  C1 @ [0, 33.55MB)  (dead after k_gemm2; region reused below)
  //    Mk    @ 0          (16.78MB)  [512][32][256]
  //    warr  @ 16777216   (2MB)      [512][32][32]
  //    wc    @ 18874368   (64KB)     [512][32]
  //    keyrT @ 18939904   (526KB)    [257][512]
  //    h     @ 19466240   (1MB)      [512][512]
  //  zp @ 33554432        (8.4MB)    [512][32][128]
  float* C1    = (float*)(ws);
  float* Mk    = (float*)(ws);
  float* warr  = (float*)(ws + 16777216);
  float* wcb   = (float*)(ws + 18874368);
  float* keyrT = (float*)(ws + 18939904);
  float* h     = (float*)(ws + 19466240);
  float* zp    = (float*)(ws + 33554432);

  hipLaunchKernelGGL(k_gemm1, dim3(1024), dim3(256), 0, stream, x, w1, b1, C1);
  hipLaunchKernelGGL(k_gemm2, dim3(512), dim3(256), 0, stream, C1, w2, b2, zp);
  hipLaunchKernelGGL(k_gram, dim3(512), dim3(256), 0, stream, zp, warr, wcb, cg, cb);
  for (int t = 0; t <= 32; t++) {
    hipLaunchKernelGGL(k_gates, dim3(1024), dim3(256), 0, stream, Wx, lb, keyrT, h, t);
    if (t < 32) {
      hipLaunchKernelGGL(k_update, dim3(512), dim3(256), 0, stream,
                         h, kW, kb, gW, gb, warr, wcb, Mk, keyrT, t);
    }
  }
  hipLaunchKernelGGL(k_y, dim3(128), dim3(256), 0, stream, h, yW, yb, out);
}